// Round 2
// baseline (595.512 us; speedup 1.0000x reference)
//
#include <hip/hip_runtime.h>
#include <hip/hip_bf16.h>
#include <math.h>

typedef __bf16 bf16;
typedef bf16  bf16x8 __attribute__((ext_vector_type(8)));
typedef bf16  bf16x4 __attribute__((ext_vector_type(4)));
typedef float f32x4  __attribute__((ext_vector_type(4)));

#define SLEN 2048
#define HID  3584
#define NH   28
#define NKV  4
#define HD   128
#define QKVN 4608   /* 3584 q + 512 k + 512 v */

static __device__ __forceinline__ f32x4 mfma16(bf16x8 a, bf16x8 b, f32x4 c) {
    return __builtin_amdgcn_mfma_f32_16x16x32_bf16(a, b, c, 0, 0, 0);
}

// ---------------------------------------------------------------------------
// fp32 -> bf16 bulk convert, 4 elems/thread, exact grid (n % 1024 == 0)
// ---------------------------------------------------------------------------
__global__ __launch_bounds__(256) void cvt_f2b(const float* __restrict__ in,
                                               bf16* __restrict__ out) {
    int i = blockIdx.x * 256 + threadIdx.x;
    float4 v = ((const float4*)in)[i];
    bf16x4 o = { (bf16)v.x, (bf16)v.y, (bf16)v.z, (bf16)v.w };
    ((bf16x4*)out)[i] = o;
}

// ---------------------------------------------------------------------------
// Tile transpose (+ optional fp32->bf16): out[c + row_off][r] = in[r][c].
// Dims multiple of 32.
// ---------------------------------------------------------------------------
template <typename TIN>
__global__ __launch_bounds__(256) void tr_kernel(const TIN* __restrict__ in,
                                                 bf16* __restrict__ out,
                                                 int in_stride, int out_stride,
                                                 int row_off) {
    __shared__ TIN t[32][33];
    int tx = threadIdx.x & 31, ty = threadIdx.x >> 5;   // ty 0..7
    int r0 = blockIdx.y * 32, c0 = blockIdx.x * 32;
#pragma unroll
    for (int i = 0; i < 4; i++) {
        int r = ty + i * 8;
        t[r][tx] = in[(size_t)(r0 + r) * in_stride + c0 + tx];
    }
    __syncthreads();
#pragma unroll
    for (int i = 0; i < 4; i++) {
        int c = ty + i * 8;
        out[(size_t)(c0 + c + row_off) * out_stride + r0 + tx] = (bf16)t[tx][c];
    }
}

// ---------------------------------------------------------------------------
// GEMM: C[M][N] = A[M][Kd] * BT[N][Kd]^T   (bf16 in, CT out, fp32 MFMA accum)
// 128x128 block tile, BK=32, 256 thr = 4 waves, each wave 64x64 (4x4 MFMA).
// LDS row stride 40 elems (80B): b128 frag reads spread uniformly over banks.
// ---------------------------------------------------------------------------
template <typename CT>
__global__ __launch_bounds__(256) void gemm_bt(const bf16* __restrict__ A,
                                               const bf16* __restrict__ BT,
                                               CT* __restrict__ C,
                                               int M, int N, int Kd) {
    __shared__ __align__(16) bf16 As[128 * 40];
    __shared__ __align__(16) bf16 Bs[128 * 40];
    int tid  = threadIdx.x;
    int lane = tid & 63, wave = tid >> 6;
    int fn = lane & 15, qd = lane >> 4;
    int wm = (wave & 1) * 64, wn = (wave >> 1) * 64;
    int m0 = blockIdx.y * 128, n0 = blockIdx.x * 128;

    f32x4 acc[4][4];
#pragma unroll
    for (int a = 0; a < 4; a++)
#pragma unroll
        for (int b = 0; b < 4; b++) acc[a][b] = (f32x4){0.f, 0.f, 0.f, 0.f};

    int r_a = tid >> 2;            // 0..63
    int c8  = (tid & 3) * 8;       // 0,8,16,24
    const bf16* Ap = A  + (size_t)(m0 + r_a) * Kd + c8;
    const bf16* Bp = BT + (size_t)(n0 + r_a) * Kd + c8;

    for (int k0 = 0; k0 < Kd; k0 += 32) {
        *(bf16x8*)(As + r_a * 40 + c8)        = *(const bf16x8*)(Ap + k0);
        *(bf16x8*)(As + (r_a + 64) * 40 + c8) = *(const bf16x8*)(Ap + (size_t)64 * Kd + k0);
        *(bf16x8*)(Bs + r_a * 40 + c8)        = *(const bf16x8*)(Bp + k0);
        *(bf16x8*)(Bs + (r_a + 64) * 40 + c8) = *(const bf16x8*)(Bp + (size_t)64 * Kd + k0);
        __syncthreads();

        bf16x8 af[4], bfv[4];
#pragma unroll
        for (int t = 0; t < 4; t++)
            af[t] = *(const bf16x8*)(As + (wm + t * 16 + fn) * 40 + qd * 8);
#pragma unroll
        for (int t = 0; t < 4; t++)
            bfv[t] = *(const bf16x8*)(Bs + (wn + t * 16 + fn) * 40 + qd * 8);
#pragma unroll
        for (int tm = 0; tm < 4; tm++)
#pragma unroll
            for (int tn = 0; tn < 4; tn++)
                acc[tm][tn] = mfma16(af[tm], bfv[tn], acc[tm][tn]);
        __syncthreads();
    }

    // Epilogue: C/D layout col = lane&15, row = (lane>>4)*4 + i  [m89/m91]
#pragma unroll
    for (int tm = 0; tm < 4; tm++)
#pragma unroll
        for (int tn = 0; tn < 4; tn++) {
            int row = m0 + wm + tm * 16 + qd * 4;
            int col = n0 + wn + tn * 16 + fn;
            CT* cp = C + (size_t)row * N + col;
#pragma unroll
            for (int i = 0; i < 4; i++) cp[(size_t)i * N] = (CT)acc[tm][tn][i];
        }
}

// ---------------------------------------------------------------------------
// RoPE: QKV[s][.] -> Qb[s][28*128] and Kb[s][4*128] (rotated), V untouched.
// out[d]    = x[d]*cos(a_d)   - x[d+64]*sin(a_d)
// out[d+64] = x[d+64]*cos(a_d) + x[d]*sin(a_d),  a_d = pos * theta^(-d/64)
// ---------------------------------------------------------------------------
__global__ __launch_bounds__(256) void rope_kernel(const bf16* __restrict__ QKV,
                                                   const int* __restrict__ pos_ids,
                                                   bf16* __restrict__ Qb,
                                                   bf16* __restrict__ Kb) {
    int s = blockIdx.x;
    float pos = (float)pos_ids[s];
    const bf16* row = QKV + (size_t)s * QKVN;
    const float kf = 19.931568569324174f / 64.0f;   // log2(1e6)/64
#pragma unroll
    for (int i = 0; i < 8; i++) {
        int idx = threadIdx.x + i * 256;    // 0..2047 = 32 heads * 64 pairs
        int hh = idx >> 6, d = idx & 63;
        float ang = pos * exp2f(-(float)d * kf);
        float sn, cs;
        sincosf(ang, &sn, &cs);
        int base = (hh < NH) ? hh * HD : HID + (hh - NH) * HD;
        float x1 = (float)row[base + d];
        float x2 = (float)row[base + d + 64];
        float o1 = x1 * cs - x2 * sn;
        float o2 = x2 * cs + x1 * sn;
        if (hh < NH) {
            bf16* q = Qb + (size_t)s * HID + hh * HD + d;
            q[0]  = (bf16)o1;
            q[64] = (bf16)o2;
        } else {
            bf16* kp = Kb + (size_t)s * (NKV * HD) + (hh - NH) * HD + d;
            kp[0]  = (bf16)o1;
            kp[64] = (bf16)o2;
        }
    }
}

// ---------------------------------------------------------------------------
// Flash attention, causal + pad mask, GQA (7 q-heads per kv-head).
// Block: one head, 64 q-rows. 4 waves x 16 q-rows. K/V tiles of 64 staged in
// LDS. Online softmax in MFMA C-layout; P -> A-layout via per-wave LDS.
// ---------------------------------------------------------------------------
__global__ __launch_bounds__(256) void attn_kernel(const bf16* __restrict__ Qb,
                                                   const bf16* __restrict__ Kb,
                                                   const bf16* __restrict__ VTb,
                                                   const int* __restrict__ amask,
                                                   bf16* __restrict__ Ob) {
    __shared__ __align__(16) bf16 Ks[64 * 136];     // [kpos][d]
    __shared__ __align__(16) bf16 VTs[128 * 72];    // [d][kpos]
    __shared__ __align__(16) bf16 Ps[4 * 16 * 72];  // per-wave P round-trip
    __shared__ float ms[64];                        // additive pad mask

    int tid  = threadIdx.x;
    int lane = tid & 63, wave = tid >> 6;
    int fn = lane & 15, qd = lane >> 4;
    int h = blockIdx.y, kvh = h / (NH / NKV);
    int qbase = blockIdx.x * 64;
    int qrow  = qbase + wave * 16;          // wave's 16-row block
    bf16* Pw = Ps + wave * 16 * 72;

    // Q fragments (A-operand: m = lane&15, k = quad*8+j), 128 dims = 4 chunks
    bf16x8 qf[4];
    const bf16* qp = Qb + (size_t)(qrow + fn) * HID + h * HD + qd * 8;
#pragma unroll
    for (int c = 0; c < 4; c++) qf[c] = *(const bf16x8*)(qp + c * 32);

    f32x4 oacc[8];
#pragma unroll
    for (int d = 0; d < 8; d++) oacc[d] = (f32x4){0.f, 0.f, 0.f, 0.f};
    float mrow[4] = {-3.0e38f, -3.0e38f, -3.0e38f, -3.0e38f};
    float lrow[4] = {0.f, 0.f, 0.f, 0.f};

    const float scale = 0.08838834764831845f;   // 1/sqrt(128)
    const float L2E = 1.4426950408889634f;

    int nkt = blockIdx.x + 1;   // causal: k tiles 0..qtile
    for (int kt = 0; kt < nkt; kt++) {
        int kb = kt * 64;
        // ---- stage K tile [64][128] ----
#pragma unroll
        for (int i = 0; i < 4; i++) {
            int cid = tid + i * 256;           // 0..1023
            int r = cid >> 4, cc = cid & 15;
            *(bf16x8*)(Ks + r * 136 + cc * 8) =
                *(const bf16x8*)(Kb + (size_t)(kb + r) * (NKV * HD) + kvh * HD + cc * 8);
        }
        // ---- stage V^T tile [128][64] ----
#pragma unroll
        for (int i = 0; i < 4; i++) {
            int cid = tid + i * 256;
            int d = cid >> 3, sc = cid & 7;
            *(bf16x8*)(VTs + d * 72 + sc * 8) =
                *(const bf16x8*)(VTb + (size_t)(kvh * HD + d) * SLEN + kb + sc * 8);
        }
        if (tid < 64) ms[tid] = amask[kb + tid] ? 0.f : -1.0e30f;
        __syncthreads();

        // ---- S = Q K^T ----
        f32x4 sacc[4];
#pragma unroll
        for (int nt = 0; nt < 4; nt++) {
            sacc[nt] = (f32x4){0.f, 0.f, 0.f, 0.f};
#pragma unroll
            for (int c = 0; c < 4; c++) {
                bf16x8 kfr = *(const bf16x8*)(Ks + (nt * 16 + fn) * 136 + c * 32 + qd * 8);
                sacc[nt] = mfma16(qf[c], kfr, sacc[nt]);
            }
        }

        // ---- online softmax (C-layout: col=fn, rows qd*4+i) ----
        float sv[4][4], rmax[4];
#pragma unroll
        for (int i = 0; i < 4; i++) rmax[i] = -3.0e38f;
#pragma unroll
        for (int nt = 0; nt < 4; nt++) {
            float madd = ms[nt * 16 + fn];
            int col = kb + nt * 16 + fn;
#pragma unroll
            for (int i = 0; i < 4; i++) {
                int row = qrow + qd * 4 + i;
                float x = sacc[nt][i] * scale + madd;
                if (col > row) x = -3.0e38f;            // causal
                sv[nt][i] = x;
                rmax[i] = fmaxf(rmax[i], x);
            }
        }
#pragma unroll
        for (int off = 1; off < 16; off <<= 1)
#pragma unroll
            for (int i = 0; i < 4; i++)
                rmax[i] = fmaxf(rmax[i], __shfl_xor(rmax[i], off, 16));

        float alpha[4], psum[4];
#pragma unroll
        for (int i = 0; i < 4; i++) {
            float mnew = fmaxf(mrow[i], rmax[i]);
            alpha[i] = exp2f((mrow[i] - mnew) * L2E);
            mrow[i] = mnew;
            psum[i] = 0.f;
        }
#pragma unroll
        for (int nt = 0; nt < 4; nt++)
#pragma unroll
            for (int i = 0; i < 4; i++) {
                float p = exp2f((sv[nt][i] - mrow[i]) * L2E);
                psum[i] += p;
                Pw[(qd * 4 + i) * 72 + nt * 16 + fn] = (bf16)p;
            }
#pragma unroll
        for (int off = 1; off < 16; off <<= 1)
#pragma unroll
            for (int i = 0; i < 4; i++) psum[i] += __shfl_xor(psum[i], off, 16);
#pragma unroll
        for (int i = 0; i < 4; i++) lrow[i] = lrow[i] * alpha[i] + psum[i];
#pragma unroll
        for (int d = 0; d < 8; d++)
#pragma unroll
            for (int i = 0; i < 4; i++) oacc[d][i] *= alpha[i];

        // ---- O += P V (P via LDS round-trip to A-layout; same-wave dep,
        //      compiler orders via lgkmcnt) ----
        bf16x8 pf0 = *(const bf16x8*)(Pw + fn * 72 + qd * 8);
        bf16x8 pf1 = *(const bf16x8*)(Pw + fn * 72 + 32 + qd * 8);
#pragma unroll
        for (int d = 0; d < 8; d++) {
            bf16x8 vf0 = *(const bf16x8*)(VTs + (d * 16 + fn) * 72 + qd * 8);
            bf16x8 vf1 = *(const bf16x8*)(VTs + (d * 16 + fn) * 72 + 32 + qd * 8);
            oacc[d] = mfma16(pf0, vf0, oacc[d]);
            oacc[d] = mfma16(pf1, vf1, oacc[d]);
        }
        __syncthreads();
    }

    // ---- epilogue: normalize, store [s][h*128+d] ----
    float invl[4];
#pragma unroll
    for (int i = 0; i < 4; i++) invl[i] = 1.f / lrow[i];
#pragma unroll
    for (int d = 0; d < 8; d++) {
        int col = h * HD + d * 16 + fn;
#pragma unroll
        for (int i = 0; i < 4; i++) {
            int row = qrow + qd * 4 + i;
            Ob[(size_t)row * HID + col] = (bf16)(oacc[d][i] * invl[i]);
        }
    }
}

// ---------------------------------------------------------------------------
extern "C" void kernel_launch(void* const* d_in, const int* in_sizes, int n_in,
                              void* d_out, int out_size, void* d_ws, size_t ws_size,
                              hipStream_t stream) {
    const float* X     = (const float*)d_in[0];   // fp32 per reference
    const int*   amask = (const int*)d_in[1];
    const int*   pos   = (const int*)d_in[2];
    const float* Wq    = (const float*)d_in[3];
    const float* Wk    = (const float*)d_in[4];
    const float* Wv    = (const float*)d_in[5];
    const float* Wo    = (const float*)d_in[6];
    float* out = (float*)d_out;                   // fp32 per reference output

    // ws layout (bytes), with region reuse to stay small (~85.5 MB):
    //  [0)          WT [4608][3584] bf16 (33,030,144 B)  -> later reused as WoT
    //  [33030144)   QKV [2048][4608] bf16 (18,874,368 B) -> later reused as Ob
    //  [51904512)   Xb  [2048][3584] bf16 (14,680,064 B)
    //  [66584576)   Qb  [2048][3584] bf16 (14,680,064 B)
    //  [81264640)   Kb  [2048][512]  bf16 ( 2,097,152 B)
    //  [83361792)   VTb [512][2048]  bf16 ( 2,097,152 B)   end: 85,458,944
    char* w = (char*)d_ws;
    bf16* WT  = (bf16*)w;
    bf16* WoT = WT;                               // reuse after QKV GEMM
    bf16* QKV = (bf16*)(w + 33030144);
    bf16* Ob  = QKV;                              // reuse after rope + trV
    bf16* Xb  = (bf16*)(w + 51904512);
    bf16* Qb  = (bf16*)(w + 66584576);
    bf16* Kb  = (bf16*)(w + 81264640);
    bf16* VTb = (bf16*)(w + 83361792);

    // X fp32 -> bf16 (2048*3584 / 1024 = 7168 blocks)
    cvt_f2b<<<7168, 256, 0, stream>>>(X, Xb);

    // weight transposes (+downconvert): WT rows = [Wq^T ; Wk^T ; Wv^T]
    tr_kernel<float><<<dim3(112, 112), 256, 0, stream>>>(Wq, WT, HID, HID, 0);
    tr_kernel<float><<<dim3(16, 112), 256, 0, stream>>>(Wk, WT, NKV * HD, HID, HID);
    tr_kernel<float><<<dim3(16, 112), 256, 0, stream>>>(Wv, WT, NKV * HD, HID, HID + NKV * HD);

    // fused QKV projection (bf16 out)
    gemm_bt<bf16><<<dim3(QKVN / 128, SLEN / 128), 256, 0, stream>>>(Xb, WT, QKV, SLEN, QKVN, HID);

    // RoPE (q,k) and V -> V^T [d][s]
    rope_kernel<<<SLEN, 256, 0, stream>>>(QKV, pos, Qb, Kb);
    tr_kernel<bf16><<<dim3(16, 64), 256, 0, stream>>>(QKV + HID + NKV * HD, VTb, QKVN, SLEN, 0);

    // Wo transpose into the (now dead) WT region
    tr_kernel<float><<<dim3(112, 112), 256, 0, stream>>>(Wo, WoT, HID, HID, 0);

    // attention -> Ob (reuses QKV region, dead after rope+trV)
    attn_kernel<<<dim3(SLEN / 64, NH), 256, 0, stream>>>(Qb, Kb, VTb, amask, Ob);

    // output projection, fp32 out
    gemm_bt<float><<<dim3(HID / 128, SLEN / 128), 256, 0, stream>>>(Ob, WoT, out, SLEN, HID, HID);
}

// Round 3
// 524.671 us; speedup vs baseline: 1.1350x; 1.1350x over previous
//
#include <hip/hip_runtime.h>
#include <hip/hip_bf16.h>
#include <math.h>

typedef __bf16 bf16;
typedef bf16  bf16x8 __attribute__((ext_vector_type(8)));
typedef bf16  bf16x4 __attribute__((ext_vector_type(4)));
typedef float f32x4  __attribute__((ext_vector_type(4)));

#define SLEN 2048
#define HID  3584
#define NH   28
#define NKV  4
#define HD   128
#define QKVN 4608   /* 3584 q + 512 k + 512 v */
#define KROW 512    /* NKV*HD */

static __device__ __forceinline__ f32x4 mfma16(bf16x8 a, bf16x8 b, f32x4 c) {
    return __builtin_amdgcn_mfma_f32_16x16x32_bf16(a, b, c, 0, 0, 0);
}

// async global->LDS DMA, 16B per lane; LDS dest = wave-uniform base + lane*16
static __device__ __forceinline__ void gl_lds16(const bf16* g, bf16* l) {
    __builtin_amdgcn_global_load_lds(
        (const __attribute__((address_space(1))) void*)g,
        (__attribute__((address_space(3))) void*)l, 16, 0, 0);
}

// ---------------------------------------------------------------------------
// fp32 -> bf16 bulk convert, 4 elems/thread, exact grid (n % 1024 == 0)
// ---------------------------------------------------------------------------
__global__ __launch_bounds__(256) void cvt_f2b(const float* __restrict__ in,
                                               bf16* __restrict__ out) {
    int i = blockIdx.x * 256 + threadIdx.x;
    float4 v = ((const float4*)in)[i];
    bf16x4 o = { (bf16)v.x, (bf16)v.y, (bf16)v.z, (bf16)v.w };
    ((bf16x4*)out)[i] = o;
}

// ---------------------------------------------------------------------------
// Tile transpose (+ optional fp32->bf16): out[c + row_off][r] = in[r][c].
// ---------------------------------------------------------------------------
template <typename TIN>
__global__ __launch_bounds__(256) void tr_kernel(const TIN* __restrict__ in,
                                                 bf16* __restrict__ out,
                                                 int in_stride, int out_stride,
                                                 int row_off) {
    __shared__ TIN t[32][33];
    int tx = threadIdx.x & 31, ty = threadIdx.x >> 5;   // ty 0..7
    int r0 = blockIdx.y * 32, c0 = blockIdx.x * 32;
#pragma unroll
    for (int i = 0; i < 4; i++) {
        int r = ty + i * 8;
        t[r][tx] = in[(size_t)(r0 + r) * in_stride + c0 + tx];
    }
    __syncthreads();
#pragma unroll
    for (int i = 0; i < 4; i++) {
        int c = ty + i * 8;
        out[(size_t)(c0 + c + row_off) * out_stride + r0 + tx] = (bf16)t[tx][c];
    }
}

// ---------------------------------------------------------------------------
// GEMM (m97 structure): C[M][N] = A[M][Kd] * BT[N][Kd]^T
// 128x128 tile, BK=32, 256 thr = 4 waves, 64x64/wave (4x4 MFMA).
// Staging via global_load_lds 16B; LDS unpadded [128][32] (64B row stride).
// ---------------------------------------------------------------------------
template <typename CT>
__global__ __launch_bounds__(256) void gemm_bt(const bf16* __restrict__ A,
                                               const bf16* __restrict__ BT,
                                               CT* __restrict__ C,
                                               int M, int N, int Kd) {
    __shared__ __align__(16) bf16 As[128 * 32];
    __shared__ __align__(16) bf16 Bs[128 * 32];
    int tid  = threadIdx.x;
    int lane = tid & 63, wave = tid >> 6;
    int fn = lane & 15, qd = lane >> 4;
    int wm = (wave & 1) * 64, wn = (wave >> 1) * 64;
    int m0 = blockIdx.y * 128, n0 = blockIdx.x * 128;

    f32x4 acc[4][4];
#pragma unroll
    for (int a = 0; a < 4; a++)
#pragma unroll
        for (int b = 0; b < 4; b++) acc[a][b] = (f32x4){0.f, 0.f, 0.f, 0.f};

    int rsub = lane >> 2;          // 0..15
    int c8   = (lane & 3) * 8;     // 0,8,16,24
    const bf16* a0 = A  + (size_t)(m0 + (wave * 2 + 0) * 16 + rsub) * Kd + c8;
    const bf16* a1 = A  + (size_t)(m0 + (wave * 2 + 1) * 16 + rsub) * Kd + c8;
    const bf16* b0 = BT + (size_t)(n0 + (wave * 2 + 0) * 16 + rsub) * Kd + c8;
    const bf16* b1 = BT + (size_t)(n0 + (wave * 2 + 1) * 16 + rsub) * Kd + c8;
    bf16* la0 = As + (wave * 2 + 0) * 512;
    bf16* la1 = As + (wave * 2 + 1) * 512;
    bf16* lb0 = Bs + (wave * 2 + 0) * 512;
    bf16* lb1 = Bs + (wave * 2 + 1) * 512;

    for (int k0 = 0; k0 < Kd; k0 += 32) {
        gl_lds16(a0 + k0, la0);
        gl_lds16(a1 + k0, la1);
        gl_lds16(b0 + k0, lb0);
        gl_lds16(b1 + k0, lb1);
        __syncthreads();

        bf16x8 af[4], bfv[4];
#pragma unroll
        for (int t = 0; t < 4; t++)
            af[t] = *(const bf16x8*)(As + (wm + t * 16 + fn) * 32 + qd * 8);
#pragma unroll
        for (int t = 0; t < 4; t++)
            bfv[t] = *(const bf16x8*)(Bs + (wn + t * 16 + fn) * 32 + qd * 8);
#pragma unroll
        for (int tm = 0; tm < 4; tm++)
#pragma unroll
            for (int tn = 0; tn < 4; tn++)
                acc[tm][tn] = mfma16(af[tm], bfv[tn], acc[tm][tn]);
        __syncthreads();
    }

    // C/D layout: col = lane&15, row = (lane>>4)*4 + i  [m89/m91]
#pragma unroll
    for (int tm = 0; tm < 4; tm++)
#pragma unroll
        for (int tn = 0; tn < 4; tn++) {
            int row = m0 + wm + tm * 16 + qd * 4;
            int col = n0 + wn + tn * 16 + fn;
            CT* cp = C + (size_t)row * N + col;
#pragma unroll
            for (int i = 0; i < 4; i++) cp[(size_t)i * N] = (CT)acc[tm][tn][i];
        }
}

// ---------------------------------------------------------------------------
// RoPE: QKV[s][.] -> Qb[s][28*128], Kb[s][4*128] (rotated).
// ---------------------------------------------------------------------------
__global__ __launch_bounds__(256) void rope_kernel(const bf16* __restrict__ QKV,
                                                   const int* __restrict__ pos_ids,
                                                   bf16* __restrict__ Qb,
                                                   bf16* __restrict__ Kb) {
    int s = blockIdx.x;
    float pos = (float)pos_ids[s];
    const bf16* row = QKV + (size_t)s * QKVN;
    const float kf = 19.931568569324174f / 64.0f;   // log2(1e6)/64
#pragma unroll
    for (int i = 0; i < 8; i++) {
        int idx = threadIdx.x + i * 256;    // 32 heads * 64 pairs
        int hh = idx >> 6, d = idx & 63;
        float ang = pos * exp2f(-(float)d * kf);
        float sn, cs;
        sincosf(ang, &sn, &cs);
        int base = (hh < NH) ? hh * HD : HID + (hh - NH) * HD;
        float x1 = (float)row[base + d];
        float x2 = (float)row[base + d + 64];
        float o1 = x1 * cs - x2 * sn;
        float o2 = x2 * cs + x1 * sn;
        if (hh < NH) {
            bf16* q = Qb + (size_t)s * HID + hh * HD + d;
            q[0]  = (bf16)o1;
            q[64] = (bf16)o2;
        } else {
            bf16* kp = Kb + (size_t)s * KROW + (hh - NH) * HD + d;
            kp[0]  = (bf16)o1;
            kp[64] = (bf16)o2;
        }
    }
}

// ---------------------------------------------------------------------------
// Flash attention, causal + pad, GQA. Block = q-tile pair (i, 31-i) x head:
// grid 16x28, every block exactly 33 compute-iterations (balanced).
// S^T via MFMA(K,Q): softmax per-lane (q=fn), 4 shuffles/iter, bf16x4 P-writes.
// K/V staged via global_load_lds into chunk-planes (64B row stride).
// ---------------------------------------------------------------------------
__global__ __launch_bounds__(256) void attn_kernel(const bf16* __restrict__ Qb,
                                                   const bf16* __restrict__ Kb,
                                                   const bf16* __restrict__ VTb,
                                                   const int* __restrict__ amask,
                                                   bf16* __restrict__ Ob) {
    __shared__ __align__(16) bf16 Ks[4][64 * 32];    // plane c: K[kpos][c*32+0..32)
    __shared__ __align__(16) bf16 VTs[2][128 * 32];  // plane p: VT[d][p*32+0..32)
    __shared__ __align__(16) bf16 Ps[4][16 * 72];    // per-wave P [q][kpos], stride 72
    __shared__ __align__(16) float alf[4][16];       // per-wave alpha strip
    __shared__ __align__(16) float ms[64];           // additive pad mask

    int tid  = threadIdx.x;
    int lane = tid & 63, wave = tid >> 6;
    int fn = lane & 15, qd = lane >> 4;
    int ib = blockIdx.x, h = blockIdx.y, kvh = h / (NH / NKV);
    int ktL = ib, ktH = 31 - ib;
    int rowL = ib * 64 + wave * 16;
    int rowH = (31 - ib) * 64 + wave * 16;
    int rsub = lane >> 2, c8 = (lane & 3) * 8;

    bf16*  Pw  = Ps[wave];
    float* alw = alf[wave];

    // Q fragments (B-operand for S^T and A-layout share lane mapping)
    bf16x8 qfl[4], qfh[4];
    {
        const bf16* pl = Qb + (size_t)(rowL + fn) * HID + h * HD + qd * 8;
        const bf16* ph = Qb + (size_t)(rowH + fn) * HID + h * HD + qd * 8;
#pragma unroll
        for (int c = 0; c < 4; c++) {
            qfl[c] = *(const bf16x8*)(pl + c * 32);
            qfh[c] = *(const bf16x8*)(ph + c * 32);
        }
    }

    f32x4 oaccL[8], oaccH[8];
#pragma unroll
    for (int d = 0; d < 8; d++) {
        oaccL[d] = (f32x4){0.f, 0.f, 0.f, 0.f};
        oaccH[d] = (f32x4){0.f, 0.f, 0.f, 0.f};
    }
    float mLo = -3.0e38f, lLo = 0.f, mHi = -3.0e38f, lHi = 0.f;

    const float scale = 0.08838834764831845f;   // 1/sqrt(128)
    const float L2E = 1.4426950408889634f;

    // one k-tile step for one q-tile (16 q-rows/wave)
    auto process = [&](int kb, int qrow, bf16x8* qf, f32x4* oacc,
                       float& mrow, float& lrow) {
        f32x4 sacc[4];
#pragma unroll
        for (int nt = 0; nt < 4; nt++) {
            sacc[nt] = (f32x4){0.f, 0.f, 0.f, 0.f};
#pragma unroll
            for (int c = 0; c < 4; c++) {
                bf16x8 kfr = *(const bf16x8*)&Ks[c][(nt * 16 + fn) * 32 + qd * 8];
                sacc[nt] = mfma16(kfr, qf[c], sacc[nt]);   // D[m=kpos][n=q]
            }
        }
        // S^T C-layout: q = fn, kpos = kb + nt*16 + qd*4 + ii
        int dq = qrow + fn - kb - qd * 4;    // mask where nt*16+ii > dq
        float sv[16], rmx = -3.0e38f;
#pragma unroll
        for (int nt = 0; nt < 4; nt++) {
            f32x4 mv = *(const f32x4*)&ms[nt * 16 + qd * 4];
#pragma unroll
            for (int ii = 0; ii < 4; ii++) {
                float x = sacc[nt][ii] * scale + mv[ii];
                if (nt * 16 + ii > dq) x = -3.0e38f;       // causal
                sv[nt * 4 + ii] = x;
                rmx = fmaxf(rmx, x);
            }
        }
        rmx = fmaxf(rmx, __shfl_xor(rmx, 16));
        rmx = fmaxf(rmx, __shfl_xor(rmx, 32));
        float mnew = fmaxf(mrow, rmx);
        float al = exp2f((mrow - mnew) * L2E);
        mrow = mnew;
        float ps = 0.f;
#pragma unroll
        for (int nt = 0; nt < 4; nt++) {
            bf16x4 pk;
#pragma unroll
            for (int ii = 0; ii < 4; ii++) {
                float p = exp2f((sv[nt * 4 + ii] - mnew) * L2E);
                ps += p;
                pk[ii] = (bf16)p;
            }
            *(bf16x4*)&Pw[fn * 72 + nt * 16 + qd * 4] = pk;   // contiguous kpos
        }
        ps += __shfl_xor(ps, 16);
        ps += __shfl_xor(ps, 32);
        lrow = lrow * al + ps;
        if (lane < 16) alw[lane] = al;                     // redistribute alpha
        f32x4 av = *(const f32x4*)&alw[qd * 4];            // same-wave, in-order
        bf16x8 pf0 = *(const bf16x8*)&Pw[fn * 72 + qd * 8];
        bf16x8 pf1 = *(const bf16x8*)&Pw[fn * 72 + 32 + qd * 8];
#pragma unroll
        for (int dt = 0; dt < 8; dt++) {
#pragma unroll
            for (int ii = 0; ii < 4; ii++) oacc[dt][ii] *= av[ii];
            bf16x8 vf0 = *(const bf16x8*)&VTs[0][(dt * 16 + fn) * 32 + qd * 8];
            bf16x8 vf1 = *(const bf16x8*)&VTs[1][(dt * 16 + fn) * 32 + qd * 8];
            oacc[dt] = mfma16(pf0, vf0, oacc[dt]);
            oacc[dt] = mfma16(pf1, vf1, oacc[dt]);
        }
    };

    for (int kt = 0; kt <= ktH; kt++) {
        int kb = kt * 64;
        // stage K: 4 d-chunk planes, 1 issue/wave/plane
#pragma unroll
        for (int j = 0; j < 4; j++)
            gl_lds16(Kb + (size_t)(kb + wave * 16 + rsub) * KROW + kvh * HD + j * 32 + c8,
                     &Ks[j][wave * 512]);
        // stage V^T: 2 kpos-planes x 2 row-halves
#pragma unroll
        for (int p = 0; p < 2; p++)
#pragma unroll
            for (int jj = 0; jj < 2; jj++)
                gl_lds16(VTb + (size_t)(kvh * HD + (wave * 2 + jj) * 16 + rsub) * SLEN + kb + p * 32 + c8,
                         &VTs[p][(wave * 2 + jj) * 512]);
        if (tid < 64) ms[tid] = amask[kb + tid] ? 0.f : -1.0e30f;
        __syncthreads();

        process(kb, rowH, qfh, oaccH, mHi, lHi);
        if (kt <= ktL) process(kb, rowL, qfl, oaccL, mLo, lLo);
        __syncthreads();
    }

    // epilogue: O C-layout rows qd*4+ii, cols dt*16+fn; 1/l via alpha strip
    auto epi = [&](f32x4* oacc, float lrow, int qrow) {
        if (lane < 16) alw[lane] = 1.f / lrow;
        f32x4 lv = *(const f32x4*)&alw[qd * 4];
#pragma unroll
        for (int dt = 0; dt < 8; dt++) {
            int col = h * HD + dt * 16 + fn;
#pragma unroll
            for (int ii = 0; ii < 4; ii++)
                Ob[(size_t)(qrow + qd * 4 + ii) * HID + col] = (bf16)(oacc[dt][ii] * lv[ii]);
        }
    };
    epi(oaccH, lHi, rowH);
    epi(oaccL, lLo, rowL);
}

// ---------------------------------------------------------------------------
extern "C" void kernel_launch(void* const* d_in, const int* in_sizes, int n_in,
                              void* d_out, int out_size, void* d_ws, size_t ws_size,
                              hipStream_t stream) {
    const float* X     = (const float*)d_in[0];
    const int*   amask = (const int*)d_in[1];
    const int*   pos   = (const int*)d_in[2];
    const float* Wq    = (const float*)d_in[3];
    const float* Wk    = (const float*)d_in[4];
    const float* Wv    = (const float*)d_in[5];
    const float* Wo    = (const float*)d_in[6];
    float* out = (float*)d_out;

    // ws layout (bytes), region reuse, ~85.5 MB total
    char* w = (char*)d_ws;
    bf16* WT  = (bf16*)w;                         // [4608][3584]
    bf16* WoT = WT;                               // reuse after QKV GEMM
    bf16* QKV = (bf16*)(w + 33030144);            // [2048][4608]
    bf16* Ob  = QKV;                              // reuse after rope + trV
    bf16* Xb  = (bf16*)(w + 51904512);            // [2048][3584]
    bf16* Qb  = (bf16*)(w + 66584576);            // [2048][3584]
    bf16* Kb  = (bf16*)(w + 81264640);            // [2048][512]
    bf16* VTb = (bf16*)(w + 83361792);            // [512][2048]

    cvt_f2b<<<7168, 256, 0, stream>>>(X, Xb);

    tr_kernel<float><<<dim3(112, 112), 256, 0, stream>>>(Wq, WT, HID, HID, 0);
    tr_kernel<float><<<dim3(16, 112), 256, 0, stream>>>(Wk, WT, NKV * HD, HID, HID);
    tr_kernel<float><<<dim3(16, 112), 256, 0, stream>>>(Wv, WT, NKV * HD, HID, HID + NKV * HD);

    gemm_bt<bf16><<<dim3(QKVN / 128, SLEN / 128), 256, 0, stream>>>(Xb, WT, QKV, SLEN, QKVN, HID);

    rope_kernel<<<SLEN, 256, 0, stream>>>(QKV, pos, Qb, Kb);
    tr_kernel<bf16><<<dim3(16, 64), 256, 0, stream>>>(QKV + HID + NKV * HD, VTb, QKVN, SLEN, 0);

    tr_kernel<float><<<dim3(112, 112), 256, 0, stream>>>(Wo, WoT, HID, HID, 0);

    attn_kernel<<<dim3(16, NH), 256, 0, stream>>>(Qb, Kb, VTb, amask, Ob);

    gemm_bt<float><<<dim3(HID / 128, SLEN / 128), 256, 0, stream>>>(Ob, WoT, out, SLEN, HID, HID);
}

// Round 4
// 485.915 us; speedup vs baseline: 1.2255x; 1.0798x over previous
//
#include <hip/hip_runtime.h>
#include <hip/hip_bf16.h>
#include <math.h>

typedef __bf16 bf16;
typedef bf16  bf16x8 __attribute__((ext_vector_type(8)));
typedef bf16  bf16x4 __attribute__((ext_vector_type(4)));
typedef float f32x4  __attribute__((ext_vector_type(4)));

#define SLEN 2048
#define HID  3584
#define NH   28
#define NKV  4
#define HD   128
#define QKVN 4608   /* 3584 q + 512 k + 512 v */
#define KROW 512    /* NKV*HD */

static __device__ __forceinline__ f32x4 mfma16(bf16x8 a, bf16x8 b, f32x4 c) {
    return __builtin_amdgcn_mfma_f32_16x16x32_bf16(a, b, c, 0, 0, 0);
}

// async global->LDS DMA, 16B/lane; LDS dest = wave-uniform base + lane*16
static __device__ __forceinline__ void gl_lds16(const bf16* g, bf16* l) {
    __builtin_amdgcn_global_load_lds(
        (const __attribute__((address_space(1))) void*)g,
        (__attribute__((address_space(3))) void*)l, 16, 0, 0);
}

// ---------------------------------------------------------------------------
// fp32 -> bf16 bulk convert
// ---------------------------------------------------------------------------
__global__ __launch_bounds__(256) void cvt_f2b(const float* __restrict__ in,
                                               bf16* __restrict__ out) {
    int i = blockIdx.x * 256 + threadIdx.x;
    float4 v = ((const float4*)in)[i];
    bf16x4 o = { (bf16)v.x, (bf16)v.y, (bf16)v.z, (bf16)v.w };
    ((bf16x4*)out)[i] = o;
}

// ---------------------------------------------------------------------------
// Tile transpose (+ optional fp32->bf16): out[c + row_off][r] = in[r][c].
// ---------------------------------------------------------------------------
template <typename TIN>
__global__ __launch_bounds__(256) void tr_kernel(const TIN* __restrict__ in,
                                                 bf16* __restrict__ out,
                                                 int in_stride, int out_stride,
                                                 int row_off) {
    __shared__ TIN t[32][33];
    int tx = threadIdx.x & 31, ty = threadIdx.x >> 5;
    int r0 = blockIdx.y * 32, c0 = blockIdx.x * 32;
#pragma unroll
    for (int i = 0; i < 4; i++) {
        int r = ty + i * 8;
        t[r][tx] = in[(size_t)(r0 + r) * in_stride + c0 + tx];
    }
    __syncthreads();
#pragma unroll
    for (int i = 0; i < 4; i++) {
        int c = ty + i * 8;
        out[(size_t)(c0 + c + row_off) * out_stride + r0 + tx] = (bf16)t[tx][c];
    }
}

// ---------------------------------------------------------------------------
// GEMM: C[M][N] = A[M][Kd] * BT[N][Kd]^T
// 128x128 tile, BK=32, 4 waves (64x64 each). Double-buffered LDS, single
// barrier/iter, prefetch issued after barrier (never cold-drained).
// XOR column swizzle (c ^= (row>>1)&3) -> frag reads 2-way (free, m136).
// ---------------------------------------------------------------------------
template <typename CT>
__global__ __launch_bounds__(256) void gemm_bt(const bf16* __restrict__ A,
                                               const bf16* __restrict__ BT,
                                               CT* __restrict__ C,
                                               int M, int N, int Kd) {
    __shared__ __align__(16) bf16 As[2][128 * 32];
    __shared__ __align__(16) bf16 Bs[2][128 * 32];
    int tid  = threadIdx.x;
    int lane = tid & 63, wave = tid >> 6;
    int fn = lane & 15, qd = lane >> 4;
    int wm = (wave & 1) * 64, wn = (wave >> 1) * 64;
    int m0 = blockIdx.y * 128, n0 = blockIdx.x * 128;

    f32x4 acc[4][4];
#pragma unroll
    for (int a = 0; a < 4; a++)
#pragma unroll
        for (int b = 0; b < 4; b++) acc[a][b] = (f32x4){0.f, 0.f, 0.f, 0.f};

    int rsub = lane >> 2;                               // 0..15
    int sw8  = (((lane & 3) ^ ((rsub >> 1) & 3)) * 8);  // swizzled k-chunk
    const bf16* a0 = A  + (size_t)(m0 + (wave * 2 + 0) * 16 + rsub) * Kd + sw8;
    const bf16* a1 = A  + (size_t)(m0 + (wave * 2 + 1) * 16 + rsub) * Kd + sw8;
    const bf16* b0 = BT + (size_t)(n0 + (wave * 2 + 0) * 16 + rsub) * Kd + sw8;
    const bf16* b1 = BT + (size_t)(n0 + (wave * 2 + 1) * 16 + rsub) * Kd + sw8;

    auto stage = [&](int it, int b) {
        int k0 = it * 32;
        gl_lds16(a0 + k0, &As[b][(wave * 2 + 0) * 512]);
        gl_lds16(a1 + k0, &As[b][(wave * 2 + 1) * 512]);
        gl_lds16(b0 + k0, &Bs[b][(wave * 2 + 0) * 512]);
        gl_lds16(b1 + k0, &Bs[b][(wave * 2 + 1) * 512]);
    };

    int rc = (qd ^ ((fn >> 1) & 3)) * 8;   // swizzled read column
    int nIter = Kd >> 5;
    stage(0, 0);
    for (int it = 0; it < nIter; it++) {
        __syncthreads();
        if (it + 1 < nIter) stage(it + 1, (it + 1) & 1);
        int b = it & 1;
        bf16x8 af[4], bfv[4];
#pragma unroll
        for (int t = 0; t < 4; t++)
            af[t] = *(const bf16x8*)&As[b][(wm + t * 16 + fn) * 32 + rc];
#pragma unroll
        for (int t = 0; t < 4; t++)
            bfv[t] = *(const bf16x8*)&Bs[b][(wn + t * 16 + fn) * 32 + rc];
#pragma unroll
        for (int tm = 0; tm < 4; tm++)
#pragma unroll
            for (int tn = 0; tn < 4; tn++)
                acc[tm][tn] = mfma16(af[tm], bfv[tn], acc[tm][tn]);
    }

    // C/D layout: col = lane&15, row = (lane>>4)*4 + i  [m89/m91]
#pragma unroll
    for (int tm = 0; tm < 4; tm++)
#pragma unroll
        for (int tn = 0; tn < 4; tn++) {
            int row = m0 + wm + tm * 16 + qd * 4;
            int col = n0 + wn + tn * 16 + fn;
            CT* cp = C + (size_t)row * N + col;
#pragma unroll
            for (int i = 0; i < 4; i++) cp[(size_t)i * N] = (CT)acc[tm][tn][i];
        }
}

// ---------------------------------------------------------------------------
// RoPE: QKV[s][.] -> Qb[s][28*128], Kb[s][4*128]; also addmask[s] (float).
// ---------------------------------------------------------------------------
__global__ __launch_bounds__(256) void rope_kernel(const bf16* __restrict__ QKV,
                                                   const int* __restrict__ pos_ids,
                                                   const int* __restrict__ amask,
                                                   bf16* __restrict__ Qb,
                                                   bf16* __restrict__ Kb,
                                                   float* __restrict__ addmask) {
    int s = blockIdx.x;
    if (threadIdx.x == 0) addmask[s] = amask[s] ? 0.f : -1.0e30f;
    float pos = (float)pos_ids[s];
    const bf16* row = QKV + (size_t)s * QKVN;
    const float kf = 19.931568569324174f / 64.0f;   // log2(1e6)/64
#pragma unroll
    for (int i = 0; i < 8; i++) {
        int idx = threadIdx.x + i * 256;    // 32 heads * 64 pairs
        int hh = idx >> 6, d = idx & 63;
        float ang = pos * exp2f(-(float)d * kf);
        float sn, cs;
        sincosf(ang, &sn, &cs);
        int base = (hh < NH) ? hh * HD : HID + (hh - NH) * HD;
        float x1 = (float)row[base + d];
        float x2 = (float)row[base + d + 64];
        float o1 = x1 * cs - x2 * sn;
        float o2 = x2 * cs + x1 * sn;
        if (hh < NH) {
            bf16* q = Qb + (size_t)s * HID + hh * HD + d;
            q[0]  = (bf16)o1;
            q[64] = (bf16)o2;
        } else {
            bf16* kp = Kb + (size_t)s * KROW + (hh - NH) * HD + d;
            kp[0]  = (bf16)o1;
            kp[64] = (bf16)o2;
        }
    }
}

// ---------------------------------------------------------------------------
// Flash attention, causal + pad, GQA. Block = q-tile pair (i, 31-i) x head,
// grid 16x28, 33 compute-iters/block. S^T via MFMA(K,Q), per-lane softmax.
// Double-buffered K/V staging, single barrier/iter, prefetch after barrier.
// Mask loaded to regs BEFORE prefetch (keeps vmcnt waits fine-grained).
// ---------------------------------------------------------------------------
__global__ __launch_bounds__(256) void attn_kernel(const bf16* __restrict__ Qb,
                                                   const bf16* __restrict__ Kb,
                                                   const bf16* __restrict__ VTb,
                                                   const float* __restrict__ addmask,
                                                   bf16* __restrict__ Ob) {
    __shared__ __align__(16) bf16 Ks[2][4][64 * 32];    // [buf][d-chunk][kpos*32]
    __shared__ __align__(16) bf16 VTs[2][2][128 * 32];  // [buf][k-chunk][d*32]
    __shared__ __align__(16) bf16 Ps[4][16 * 72];       // per-wave P [q][kpos]

    int tid  = threadIdx.x;
    int lane = tid & 63, wave = tid >> 6;
    int fn = lane & 15, qd = lane >> 4;
    int ib = blockIdx.x, h = blockIdx.y, kvh = h / (NH / NKV);
    int ktL = ib, ktH = 31 - ib;
    int rowL = ib * 64 + wave * 16;
    int rowH = (31 - ib) * 64 + wave * 16;
    int rsub = lane >> 2;
    int sw8  = (((lane & 3) ^ ((rsub >> 1) & 3)) * 8);
    int rc   = (qd ^ ((fn >> 1) & 3)) * 8;

    bf16* Pw = Ps[wave];

    bf16x8 qfl[4], qfh[4];
    {
        const bf16* pl = Qb + (size_t)(rowL + fn) * HID + h * HD + qd * 8;
        const bf16* ph = Qb + (size_t)(rowH + fn) * HID + h * HD + qd * 8;
#pragma unroll
        for (int c = 0; c < 4; c++) {
            qfl[c] = *(const bf16x8*)(pl + c * 32);
            qfh[c] = *(const bf16x8*)(ph + c * 32);
        }
    }

    f32x4 oaccL[8], oaccH[8];
#pragma unroll
    for (int d = 0; d < 8; d++) {
        oaccL[d] = (f32x4){0.f, 0.f, 0.f, 0.f};
        oaccH[d] = (f32x4){0.f, 0.f, 0.f, 0.f};
    }
    float mLo = -3.0e38f, lLo = 0.f, mHi = -3.0e38f, lHi = 0.f;

    const float scale = 0.08838834764831845f;   // 1/sqrt(128)
    const float L2E = 1.4426950408889634f;

    auto stageKV = [&](int kt, int b) {
        int kb = kt * 64;
#pragma unroll
        for (int j = 0; j < 4; j++)
            gl_lds16(Kb + (size_t)(kb + wave * 16 + rsub) * KROW + kvh * HD + j * 32 + sw8,
                     &Ks[b][j][wave * 512]);
#pragma unroll
        for (int p = 0; p < 2; p++)
#pragma unroll
            for (int jj = 0; jj < 2; jj++)
                gl_lds16(VTb + (size_t)(kvh * HD + (wave * 2 + jj) * 16 + rsub) * SLEN + kb + p * 32 + sw8,
                         &VTs[b][p][(wave * 2 + jj) * 512]);
    };

    // one k-tile step for one q-tile (16 q-rows/wave)
    auto process = [&](int b, int kb, int qrow, bf16x8* qf, f32x4* oacc,
                       float& mrow, float& lrow, const f32x4* mv) {
        f32x4 sacc[4];
#pragma unroll
        for (int nt = 0; nt < 4; nt++) {
            sacc[nt] = (f32x4){0.f, 0.f, 0.f, 0.f};
#pragma unroll
            for (int c = 0; c < 4; c++) {
                bf16x8 kfr = *(const bf16x8*)&Ks[b][c][(nt * 16 + fn) * 32 + rc];
                sacc[nt] = mfma16(kfr, qf[c], sacc[nt]);   // D[m=kpos][n=q]
            }
        }
        // S^T C-layout: q = fn, kpos = kb + nt*16 + qd*4 + ii
        int dq = qrow + fn - kb - qd * 4;
        float sv[16], rmx = -3.0e38f;
#pragma unroll
        for (int nt = 0; nt < 4; nt++) {
#pragma unroll
            for (int ii = 0; ii < 4; ii++) {
                float x = sacc[nt][ii] * scale + mv[nt][ii];
                if (nt * 16 + ii > dq) x = -3.0e38f;       // causal
                sv[nt * 4 + ii] = x;
                rmx = fmaxf(rmx, x);
            }
        }
        rmx = fmaxf(rmx, __shfl_xor(rmx, 16));
        rmx = fmaxf(rmx, __shfl_xor(rmx, 32));
        float mnew = fmaxf(mrow, rmx);
        float al = exp2f((mrow - mnew) * L2E);
        mrow = mnew;
        float ps = 0.f;
#pragma unroll
        for (int nt = 0; nt < 4; nt++) {
            bf16x4 pk;
#pragma unroll
            for (int ii = 0; ii < 4; ii++) {
                float p = exp2f((sv[nt * 4 + ii] - mnew) * L2E);
                ps += p;
                pk[ii] = (bf16)p;
            }
            *(bf16x4*)&Pw[fn * 72 + nt * 16 + qd * 4] = pk;
        }
        ps += __shfl_xor(ps, 16);
        ps += __shfl_xor(ps, 32);
        lrow = lrow * al + ps;
        f32x4 av;
#pragma unroll
        for (int ii = 0; ii < 4; ii++) av[ii] = __shfl(al, qd * 4 + ii);
        bf16x8 pf0 = *(const bf16x8*)&Pw[fn * 72 + qd * 8];
        bf16x8 pf1 = *(const bf16x8*)&Pw[fn * 72 + 32 + qd * 8];
#pragma unroll
        for (int dt = 0; dt < 8; dt++) {
#pragma unroll
            for (int ii = 0; ii < 4; ii++) oacc[dt][ii] *= av[ii];
            bf16x8 vf0 = *(const bf16x8*)&VTs[b][0][(dt * 16 + fn) * 32 + rc];
            bf16x8 vf1 = *(const bf16x8*)&VTs[b][1][(dt * 16 + fn) * 32 + rc];
            oacc[dt] = mfma16(pf0, vf0, oacc[dt]);
            oacc[dt] = mfma16(pf1, vf1, oacc[dt]);
        }
    };

    stageKV(0, 0);
    for (int kt = 0; kt <= ktH; kt++) {
        int kb = kt * 64;
        __syncthreads();
        f32x4 mv[4];                     // loaded BEFORE prefetch: fine-grained vmcnt
#pragma unroll
        for (int nt = 0; nt < 4; nt++)
            mv[nt] = *(const f32x4*)&addmask[kb + nt * 16 + qd * 4];
        if (kt < ktH) stageKV(kt + 1, (kt + 1) & 1);
        int b = kt & 1;
        process(b, kb, rowH, qfh, oaccH, mHi, lHi, mv);
        if (kt <= ktL) process(b, kb, rowL, qfl, oaccL, mLo, lLo, mv);
    }

    // epilogue: O C-layout rows qd*4+ii, cols dt*16+fn
    auto epi = [&](f32x4* oacc, float lrow, int qrow) {
        float linv = 1.f / lrow;
        f32x4 lv;
#pragma unroll
        for (int ii = 0; ii < 4; ii++) lv[ii] = __shfl(linv, qd * 4 + ii);
#pragma unroll
        for (int dt = 0; dt < 8; dt++) {
            int col = h * HD + dt * 16 + fn;
#pragma unroll
            for (int ii = 0; ii < 4; ii++)
                Ob[(size_t)(qrow + qd * 4 + ii) * HID + col] = (bf16)(oacc[dt][ii] * lv[ii]);
        }
    };
    epi(oaccH, lHi, rowH);
    epi(oaccL, lLo, rowL);
}

// ---------------------------------------------------------------------------
extern "C" void kernel_launch(void* const* d_in, const int* in_sizes, int n_in,
                              void* d_out, int out_size, void* d_ws, size_t ws_size,
                              hipStream_t stream) {
    const float* X     = (const float*)d_in[0];
    const int*   amask = (const int*)d_in[1];
    const int*   pos   = (const int*)d_in[2];
    const float* Wq    = (const float*)d_in[3];
    const float* Wk    = (const float*)d_in[4];
    const float* Wv    = (const float*)d_in[5];
    const float* Wo    = (const float*)d_in[6];
    float* out = (float*)d_out;

    // ws layout (bytes), region reuse, ~85.5 MB total
    char* w = (char*)d_ws;
    bf16*  WT   = (bf16*)w;                       // [4608][3584]
    bf16*  WoT  = WT;                             // reuse after QKV GEMM
    bf16*  QKV  = (bf16*)(w + 33030144);          // [2048][4608]
    bf16*  Ob   = QKV;                            // reuse after rope + trV
    bf16*  Xb   = (bf16*)(w + 51904512);          // [2048][3584]; dead after QKV GEMM
    float* admk = (float*)(w + 51904512);         // addmask[2048] overlays dead Xb
    bf16*  Qb   = (bf16*)(w + 66584576);          // [2048][3584]
    bf16*  Kb   = (bf16*)(w + 81264640);          // [2048][512]
    bf16*  VTb  = (bf16*)(w + 83361792);          // [512][2048]

    cvt_f2b<<<7168, 256, 0, stream>>>(X, Xb);

    tr_kernel<float><<<dim3(112, 112), 256, 0, stream>>>(Wq, WT, HID, HID, 0);
    tr_kernel<float><<<dim3(16, 112), 256, 0, stream>>>(Wk, WT, NKV * HD, HID, HID);
    tr_kernel<float><<<dim3(16, 112), 256, 0, stream>>>(Wv, WT, NKV * HD, HID, HID + NKV * HD);

    gemm_bt<bf16><<<dim3(QKVN / 128, SLEN / 128), 256, 0, stream>>>(Xb, WT, QKV, SLEN, QKVN, HID);

    // Xb dead from here; admk overlays it
    rope_kernel<<<SLEN, 256, 0, stream>>>(QKV, pos, amask, Qb, Kb, admk);
    tr_kernel<bf16><<<dim3(16, 64), 256, 0, stream>>>(QKV + HID + NKV * HD, VTb, QKVN, SLEN, 0);

    tr_kernel<float><<<dim3(112, 112), 256, 0, stream>>>(Wo, WoT, HID, HID, 0);

    attn_kernel<<<dim3(16, NH), 256, 0, stream>>>(Qb, Kb, VTb, admk, Ob);

    gemm_bt<float><<<dim3(HID / 128, SLEN / 128), 256, 0, stream>>>(Ob, WoT, out, SLEN, HID, HID);
}